// Round 1
// baseline (797.979 us; speedup 1.0000x reference)
//
#include <hip/hip_runtime.h>
#include <math.h>

#define N_NODES 100000
#define N_EDGES 3200000
#define D_FEAT  512
#define D_HID   64
#define N_CLS   40
#define NBKT    391            /* coarse buckets = ceil(N/256), bucket = dst >> 8 */
#define NBLKA   256            /* blocks in passes A/B */
#define EPB     (N_EDGES / NBLKA)   /* 12500 edges per block */

typedef __attribute__((ext_vector_type(8))) short short8;
typedef __attribute__((ext_vector_type(4))) float floatx4;

static __device__ __forceinline__ unsigned short f2bf(float f) {
    unsigned u = __float_as_uint(f);
    unsigned r = (u + 0x7FFFu + ((u >> 16) & 1u)) >> 16;   // RNE
    return (unsigned short)r;
}
static __device__ __forceinline__ float bf2f(unsigned short h) {
    return __uint_as_float(((unsigned)h) << 16);
}
static __device__ __forceinline__ short8 pack_bf16x8(float4 a, float4 b) {
    short8 r;
    r[0] = (short)f2bf(a.x); r[1] = (short)f2bf(a.y);
    r[2] = (short)f2bf(a.z); r[3] = (short)f2bf(a.w);
    r[4] = (short)f2bf(b.x); r[5] = (short)f2bf(b.y);
    r[6] = (short)f2bf(b.z); r[7] = (short)f2bf(b.w);
    return r;
}

// ---------------- pass A: per-block coarse histogram (no global atomics) ----------------

__global__ __launch_bounds__(256) void k_histA(const int* __restrict__ ei,
                                               int* __restrict__ mat) {
    __shared__ int hist[NBKT];
    const int tid = threadIdx.x, blk = blockIdx.x;
    for (int i = tid; i < NBKT; i += 256) hist[i] = 0;
    __syncthreads();
    const int e0 = blk * EPB, e1 = e0 + EPB;
    for (int e = e0 + tid; e < e1; e += 256)
        atomicAdd(&hist[ei[N_EDGES + e] >> 8], 1);
    __syncthreads();
    for (int i = tid; i < NBKT; i += 256) mat[i * NBLKA + blk] = hist[i];
}

// ---------------- S1: per-bucket exclusive scan across blocks + row totals ----------------

__global__ __launch_bounds__(256) void k_scanRows(int* __restrict__ mat,
                                                  int* __restrict__ total) {
    __shared__ int s[256];
    const int tid = threadIdx.x, bin = blockIdx.x;
    int v = mat[bin * NBLKA + tid];
    s[tid] = v;
    __syncthreads();
    for (int off = 1; off < 256; off <<= 1) {
        int t = (tid >= off) ? s[tid - off] : 0;
        __syncthreads();
        s[tid] += t;
        __syncthreads();
    }
    mat[bin * NBLKA + tid] = s[tid] - v;        // exclusive within bucket
    if (tid == 255) total[bin] = s[255];
}

// ---------------- S2: scan bucket totals -> coarse_base[NBKT+1] ----------------

__global__ __launch_bounds__(512) void k_scanTot(const int* __restrict__ total,
                                                 int* __restrict__ cbase) {
    __shared__ int s[512];
    const int tid = threadIdx.x;
    int v = (tid < NBKT) ? total[tid] : 0;
    s[tid] = v;
    __syncthreads();
    for (int off = 1; off < 512; off <<= 1) {
        int t = (tid >= off) ? s[tid - off] : 0;
        __syncthreads();
        s[tid] += t;
        __syncthreads();
    }
    if (tid <= NBKT) cbase[tid] = s[tid] - v;   // tid==NBKT: v=0 -> = E
}

// ---------------- pass B: scatter edges into coarse buckets (LDS cursors only) ----------------

__global__ __launch_bounds__(256) void k_scatterB(const int* __restrict__ ei,
                                                  const float* __restrict__ ew,
                                                  const int* __restrict__ mat,
                                                  const int* __restrict__ cbase,
                                                  int2* __restrict__ tmpA,
                                                  unsigned char* __restrict__ tmpD) {
    __shared__ int cur[NBKT];
    const int tid = threadIdx.x, blk = blockIdx.x;
    for (int i = tid; i < NBKT; i += 256)
        cur[i] = cbase[i] + mat[i * NBLKA + blk];
    __syncthreads();
    const int e0 = blk * EPB, e1 = e0 + EPB;
    for (int e = e0 + tid; e < e1; e += 256) {
        int r = ei[e];
        int c = ei[N_EDGES + e];
        int slot = atomicAdd(&cur[c >> 8], 1);
        tmpA[slot] = make_int2(r, __float_as_int(ew[e]));
        tmpD[slot] = (unsigned char)(c & 255);
    }
}

// ---------------- pass C: per-bucket fine count + scan + CSR emit + dinv (deg fused) ----------------

__global__ __launch_bounds__(256) void k_bucketC(const int* __restrict__ cbase,
                                                 const int2* __restrict__ tmpA,
                                                 const unsigned char* __restrict__ tmpD,
                                                 int2* __restrict__ csr,
                                                 int* __restrict__ cnt,
                                                 int* __restrict__ base,
                                                 float* __restrict__ dinv) {
    __shared__ int   c_cnt[256];
    __shared__ float c_deg[256];
    __shared__ int   c_scan[256];
    __shared__ int   c_cur[256];
    const int tid = threadIdx.x, b = blockIdx.x;
    const int s = cbase[b], e = cbase[b + 1];
    c_cnt[tid] = 0;
    c_deg[tid] = 0.f;
    __syncthreads();
    for (int j = s + tid; j < e; j += 256) {
        int d = tmpD[j];
        atomicAdd(&c_cnt[d], 1);
        atomicAdd(&c_deg[d], __int_as_float(tmpA[j].y));
    }
    __syncthreads();
    int v = c_cnt[tid];
    c_scan[tid] = v;
    __syncthreads();
    for (int off = 1; off < 256; off <<= 1) {
        int t = (tid >= off) ? c_scan[tid - off] : 0;
        __syncthreads();
        c_scan[tid] += t;
        __syncthreads();
    }
    int excl = c_scan[tid] - v;
    c_cur[tid] = excl;
    int node = b * 256 + tid;
    if (node < N_NODES) {
        cnt[node]  = v;
        base[node] = s + excl;
        dinv[node] = rsqrtf(1.0f + c_deg[tid]);   // self-loop weight 1
    }
    __syncthreads();
    for (int j = s + tid; j < e; j += 256) {
        int d = tmpD[j];
        int slot = atomicAdd(&c_cur[d], 1);
        csr[s + slot] = tmpA[j];
    }
}

// ---------------- layer 1 GEMM via MFMA: hpre(bf16) = x @ W1 ----------------
// Block = 4 waves; wave = 16 rows x 64 cols, K=512. W1^T bf16 in LDS (64 KB),
// k-block XOR swizzle. A-frags from global in MFMA layout, cvt bf16 in-reg.

__global__ __launch_bounds__(256) void k_gemm1(const float* __restrict__ x,
                                               const float* __restrict__ W1,
                                               unsigned short* __restrict__ hpre) {
    __shared__ __align__(16) short Wt[64 * 512];   // 65536 B
    const int tid = threadIdx.x;

    {
        const int c  = tid & 63;
        const int kb = (tid >> 6) * 128;
        const int sw = (c & 7) << 3;
        for (int kk = 0; kk < 128; kk += 8) {
            short8 v;
#pragma unroll
            for (int j = 0; j < 8; j++)
                v[j] = (short)f2bf(W1[(size_t)(kb + kk + j) * D_HID + c]);
            *(short8*)&Wt[c * 512 + ((kb + kk) ^ sw)] = v;
        }
    }
    __syncthreads();

    const int widx = blockIdx.x * 4 + (tid >> 6);
    if (widx >= N_NODES / 16) return;
    const int lane = tid & 63;
    const int q  = lane >> 4;
    const int cn = lane & 15;
    const int r0 = widx * 16;
    const int sw = (cn & 7) << 3;

    floatx4 acc[4] = {{0,0,0,0},{0,0,0,0},{0,0,0,0},{0,0,0,0}};
    const float* xp = x + (size_t)(r0 + cn) * D_FEAT + q * 8;

#pragma unroll 4
    for (int k0 = 0; k0 < D_FEAT; k0 += 32) {
        float4 xa = *(const float4*)(xp + k0);
        float4 xb = *(const float4*)(xp + k0 + 4);
        short8 a = pack_bf16x8(xa, xb);
#pragma unroll
        for (int ct = 0; ct < 4; ct++) {
            short8 b = *(const short8*)&Wt[(ct * 16 + cn) * 512 + ((k0 + q * 8) ^ sw)];
            acc[ct] = __builtin_amdgcn_mfma_f32_16x16x32_bf16(a, b, acc[ct], 0, 0, 0);
        }
    }

#pragma unroll
    for (int ct = 0; ct < 4; ct++)
#pragma unroll
        for (int i = 0; i < 4; i++)
            hpre[(size_t)(r0 + q * 4 + i) * D_HID + ct * 16 + cn] = f2bf(acc[ct][i]);
}

// ---------------- layer 1 gather + fused layer-2 linear (relu(agg+b1) @ W2) ----------------
// Each wave owns one node: 64-wide hidden row lives one-element-per-lane.
// Epilogue: stash row in per-wave LDS, lanes 0..39 do the 64-step dot with W2
// (10 KB, L1-hot). Removes the separate k_gemm2 kernel and the 51 MB
// agg1 write+read round-trip.

__global__ __launch_bounds__(256) void k_gather1(const int* __restrict__ base,
                                                 const int* __restrict__ cnt,
                                                 const int2* __restrict__ csr,
                                                 const unsigned short* __restrict__ hpre,
                                                 const float* __restrict__ dinv,
                                                 const float* __restrict__ b1,
                                                 const float* __restrict__ W2,
                                                 float* __restrict__ z) {
    __shared__ float hs[4][64];
    int lane = threadIdx.x & 63;
    int w = threadIdx.x >> 6;
    int n = blockIdx.x * 4 + w;
    int s = base[n], e = s + cnt[n];
    float dn = dinv[n];
    float a0 = dn * bf2f(hpre[(size_t)n * D_HID + lane]);
    float a1 = 0.f, a2 = 0.f, a3 = 0.f, a4 = 0.f, a5 = 0.f, a6 = 0.f, a7 = 0.f;
    int j = s;
    for (; j + 7 < e; j += 8) {
        int2 p0 = csr[j];     int2 p1 = csr[j + 1];
        int2 p2 = csr[j + 2]; int2 p3 = csr[j + 3];
        int2 p4 = csr[j + 4]; int2 p5 = csr[j + 5];
        int2 p6 = csr[j + 6]; int2 p7 = csr[j + 7];
        float w0 = dinv[p0.x] * __int_as_float(p0.y);
        float w1 = dinv[p1.x] * __int_as_float(p1.y);
        float w2 = dinv[p2.x] * __int_as_float(p2.y);
        float w3 = dinv[p3.x] * __int_as_float(p3.y);
        float w4 = dinv[p4.x] * __int_as_float(p4.y);
        float w5 = dinv[p5.x] * __int_as_float(p5.y);
        float w6 = dinv[p6.x] * __int_as_float(p6.y);
        float w7 = dinv[p7.x] * __int_as_float(p7.y);
        a0 += w0 * bf2f(hpre[(size_t)p0.x * D_HID + lane]);
        a1 += w1 * bf2f(hpre[(size_t)p1.x * D_HID + lane]);
        a2 += w2 * bf2f(hpre[(size_t)p2.x * D_HID + lane]);
        a3 += w3 * bf2f(hpre[(size_t)p3.x * D_HID + lane]);
        a4 += w4 * bf2f(hpre[(size_t)p4.x * D_HID + lane]);
        a5 += w5 * bf2f(hpre[(size_t)p5.x * D_HID + lane]);
        a6 += w6 * bf2f(hpre[(size_t)p6.x * D_HID + lane]);
        a7 += w7 * bf2f(hpre[(size_t)p7.x * D_HID + lane]);
    }
    for (; j + 3 < e; j += 4) {
        int2 p0 = csr[j];     int2 p1 = csr[j + 1];
        int2 p2 = csr[j + 2]; int2 p3 = csr[j + 3];
        float w0 = dinv[p0.x] * __int_as_float(p0.y);
        float w1 = dinv[p1.x] * __int_as_float(p1.y);
        float w2 = dinv[p2.x] * __int_as_float(p2.y);
        float w3 = dinv[p3.x] * __int_as_float(p3.y);
        a0 += w0 * bf2f(hpre[(size_t)p0.x * D_HID + lane]);
        a1 += w1 * bf2f(hpre[(size_t)p1.x * D_HID + lane]);
        a2 += w2 * bf2f(hpre[(size_t)p2.x * D_HID + lane]);
        a3 += w3 * bf2f(hpre[(size_t)p3.x * D_HID + lane]);
    }
    for (; j < e; j++) {
        int2 p = csr[j];
        a0 += dinv[p.x] * __int_as_float(p.y) * bf2f(hpre[(size_t)p.x * D_HID + lane]);
    }
    float h = dn * (((a0 + a1) + (a2 + a3)) + ((a4 + a5) + (a6 + a7))) + b1[lane];
    h = h > 0.f ? h : 0.f;
    hs[w][lane] = h;
    __syncthreads();
    if (lane < N_CLS) {
        float acc = 0.f;
#pragma unroll 8
        for (int k = 0; k < D_HID; k++)
            acc += hs[w][k] * W2[k * N_CLS + lane];
        z[(size_t)n * N_CLS + lane] = acc;
    }
}

// ---------------- layer 2 gather + bias + log_softmax fused ----------------

__global__ __launch_bounds__(256) void k_gather2_lsm(const int* __restrict__ base,
                                                     const int* __restrict__ cnt,
                                                     const int2* __restrict__ csr,
                                                     const float* __restrict__ z,
                                                     const float* __restrict__ dinv,
                                                     const float* __restrict__ b2,
                                                     float* __restrict__ out) {
    int lane = threadIdx.x & 63;
    int n = blockIdx.x * 4 + (threadIdx.x >> 6);
    bool act = lane < N_CLS;
    int fl = act ? lane : (N_CLS - 1);          // clamped lane for safe loads
    int s = base[n], e = s + cnt[n];
    float dn = dinv[n];
    float a0 = dn * z[(size_t)n * N_CLS + fl];
    float a1 = 0.f, a2 = 0.f, a3 = 0.f, a4 = 0.f, a5 = 0.f, a6 = 0.f, a7 = 0.f;
    int j = s;
    for (; j + 7 < e; j += 8) {
        int2 p0 = csr[j];     int2 p1 = csr[j + 1];
        int2 p2 = csr[j + 2]; int2 p3 = csr[j + 3];
        int2 p4 = csr[j + 4]; int2 p5 = csr[j + 5];
        int2 p6 = csr[j + 6]; int2 p7 = csr[j + 7];
        float w0 = dinv[p0.x] * __int_as_float(p0.y);
        float w1 = dinv[p1.x] * __int_as_float(p1.y);
        float w2 = dinv[p2.x] * __int_as_float(p2.y);
        float w3 = dinv[p3.x] * __int_as_float(p3.y);
        float w4 = dinv[p4.x] * __int_as_float(p4.y);
        float w5 = dinv[p5.x] * __int_as_float(p5.y);
        float w6 = dinv[p6.x] * __int_as_float(p6.y);
        float w7 = dinv[p7.x] * __int_as_float(p7.y);
        a0 += w0 * z[(size_t)p0.x * N_CLS + fl];
        a1 += w1 * z[(size_t)p1.x * N_CLS + fl];
        a2 += w2 * z[(size_t)p2.x * N_CLS + fl];
        a3 += w3 * z[(size_t)p3.x * N_CLS + fl];
        a4 += w4 * z[(size_t)p4.x * N_CLS + fl];
        a5 += w5 * z[(size_t)p5.x * N_CLS + fl];
        a6 += w6 * z[(size_t)p6.x * N_CLS + fl];
        a7 += w7 * z[(size_t)p7.x * N_CLS + fl];
    }
    for (; j + 3 < e; j += 4) {
        int2 p0 = csr[j];     int2 p1 = csr[j + 1];
        int2 p2 = csr[j + 2]; int2 p3 = csr[j + 3];
        float w0 = dinv[p0.x] * __int_as_float(p0.y);
        float w1 = dinv[p1.x] * __int_as_float(p1.y);
        float w2 = dinv[p2.x] * __int_as_float(p2.y);
        float w3 = dinv[p3.x] * __int_as_float(p3.y);
        a0 += w0 * z[(size_t)p0.x * N_CLS + fl];
        a1 += w1 * z[(size_t)p1.x * N_CLS + fl];
        a2 += w2 * z[(size_t)p2.x * N_CLS + fl];
        a3 += w3 * z[(size_t)p3.x * N_CLS + fl];
    }
    for (; j < e; j++) {
        int2 p = csr[j];
        a0 += dinv[p.x] * __int_as_float(p.y) * z[(size_t)p.x * N_CLS + fl];
    }
    float logit = dn * (((a0 + a1) + (a2 + a3)) + ((a4 + a5) + (a6 + a7))) + b2[fl];
    float m = act ? logit : -INFINITY;
    for (int off = 32; off; off >>= 1) m = fmaxf(m, __shfl_xor(m, off, 64));
    float ev = act ? expf(logit - m) : 0.f;
    float sum = ev;
    for (int off = 32; off; off >>= 1) sum += __shfl_xor(sum, off, 64);
    if (act) out[(size_t)n * N_CLS + lane] = logit - m - logf(sum);
}

// ---------------- launch ----------------

extern "C" void kernel_launch(void* const* d_in, const int* in_sizes, int n_in,
                              void* d_out, int out_size, void* d_ws, size_t ws_size,
                              hipStream_t stream) {
    const float* x  = (const float*)d_in[0];
    const int*   ei = (const int*)d_in[1];
    const float* ew = (const float*)d_in[2];
    const float* W1 = (const float*)d_in[3];
    const float* b1 = (const float*)d_in[4];
    const float* W2 = (const float*)d_in[5];
    const float* b2 = (const float*)d_in[6];
    float* out = (float*)d_out;

    // workspace layout (4B words):
    //   [0,      6.4M)  csr   int2[E]
    //   [6.4M,  12.8M)  tmpA  int2[E]   -- dead after C; hpre at [6.4M, 9.6M), z at [9.6M, 13.6M)
    //   [12.8M, 13.6M)  tmpD  uchar[E]  -- dead after C; tail of z overlays it
    //   then mat / total / cbase / cnt / base / dinv
    int* ws = (int*)d_ws;
    int2*          csr  = (int2*)ws;
    int2*          tmpA = (int2*)(ws + 2 * (size_t)N_EDGES);
    unsigned char* tmpD = (unsigned char*)(ws + 4 * (size_t)N_EDGES);
    int*   mat   = ws + 4 * (size_t)N_EDGES + N_EDGES / 4;
    int*   total = mat + NBKT * NBLKA;
    int*   cbase = total + NBKT;
    int*   cnt   = cbase + NBKT + 1;
    int*   base  = cnt + N_NODES;
    float* dinv  = (float*)(base + N_NODES);
    unsigned short* hpre = (unsigned short*)tmpA;              // alias: tmpA dead after C
    float* z = (float*)(hpre + (size_t)N_NODES * D_HID);       // ends at word 13.6M = mat start ✓

    k_histA   <<<NBLKA, 256, 0, stream>>>(ei, mat);
    k_scanRows<<<NBKT,  256, 0, stream>>>(mat, total);
    k_scanTot <<<1,     512, 0, stream>>>(total, cbase);
    k_scatterB<<<NBLKA, 256, 0, stream>>>(ei, ew, mat, cbase, tmpA, tmpD);
    k_bucketC <<<NBKT,  256, 0, stream>>>(cbase, tmpA, tmpD, csr, cnt, base, dinv);
    k_gemm1   <<<(N_NODES / 16 + 3) / 4, 256, 0, stream>>>(x, W1, hpre);
    k_gather1 <<<N_NODES / 4, 256, 0, stream>>>(base, cnt, csr, hpre, dinv, b1, W2, z);
    k_gather2_lsm<<<N_NODES / 4, 256, 0, stream>>>(base, cnt, csr, z, dinv, b2, out);
}

// Round 2
// 727.035 us; speedup vs baseline: 1.0976x; 1.0976x over previous
//
#include <hip/hip_runtime.h>
#include <math.h>

#define N_NODES 100000
#define N_EDGES 3200000
#define D_FEAT  512
#define D_HID   64
#define N_CLS   40
#define ZSTR    48             /* padded z row stride (floats): 192B = always 2 aligned lines */
#define NBKT    391            /* coarse buckets = ceil(N/256), bucket = dst >> 8 */
#define NBLKA   256            /* blocks in passes A/B */
#define EPB     (N_EDGES / NBLKA)   /* 12500 edges per block */

typedef __attribute__((ext_vector_type(8))) short short8;
typedef __attribute__((ext_vector_type(4))) float floatx4;

static __device__ __forceinline__ unsigned short f2bf(float f) {
    unsigned u = __float_as_uint(f);
    unsigned r = (u + 0x7FFFu + ((u >> 16) & 1u)) >> 16;   // RNE
    return (unsigned short)r;
}
static __device__ __forceinline__ float bf2f(unsigned short h) {
    return __uint_as_float(((unsigned)h) << 16);
}
static __device__ __forceinline__ short8 pack_bf16x8(float4 a, float4 b) {
    short8 r;
    r[0] = (short)f2bf(a.x); r[1] = (short)f2bf(a.y);
    r[2] = (short)f2bf(a.z); r[3] = (short)f2bf(a.w);
    r[4] = (short)f2bf(b.x); r[5] = (short)f2bf(b.y);
    r[6] = (short)f2bf(b.z); r[7] = (short)f2bf(b.w);
    return r;
}

// ---------------- pass A: per-block coarse histogram (no global atomics) ----------------

__global__ __launch_bounds__(256) void k_histA(const int* __restrict__ ei,
                                               int* __restrict__ mat) {
    __shared__ int hist[NBKT];
    const int tid = threadIdx.x, blk = blockIdx.x;
    for (int i = tid; i < NBKT; i += 256) hist[i] = 0;
    __syncthreads();
    const int e0 = blk * EPB, e1 = e0 + EPB;
    for (int e = e0 + tid; e < e1; e += 256)
        atomicAdd(&hist[ei[N_EDGES + e] >> 8], 1);
    __syncthreads();
    for (int i = tid; i < NBKT; i += 256) mat[i * NBLKA + blk] = hist[i];
}

// ---------------- S1: per-bucket exclusive scan across blocks + row totals ----------------

__global__ __launch_bounds__(256) void k_scanRows(int* __restrict__ mat,
                                                  int* __restrict__ total) {
    __shared__ int s[256];
    const int tid = threadIdx.x, bin = blockIdx.x;
    int v = mat[bin * NBLKA + tid];
    s[tid] = v;
    __syncthreads();
    for (int off = 1; off < 256; off <<= 1) {
        int t = (tid >= off) ? s[tid - off] : 0;
        __syncthreads();
        s[tid] += t;
        __syncthreads();
    }
    mat[bin * NBLKA + tid] = s[tid] - v;        // exclusive within bucket
    if (tid == 255) total[bin] = s[255];
}

// ---------------- S2: scan bucket totals -> coarse_base[NBKT+1] ----------------

__global__ __launch_bounds__(512) void k_scanTot(const int* __restrict__ total,
                                                 int* __restrict__ cbase) {
    __shared__ int s[512];
    const int tid = threadIdx.x;
    int v = (tid < NBKT) ? total[tid] : 0;
    s[tid] = v;
    __syncthreads();
    for (int off = 1; off < 512; off <<= 1) {
        int t = (tid >= off) ? s[tid - off] : 0;
        __syncthreads();
        s[tid] += t;
        __syncthreads();
    }
    if (tid <= NBKT) cbase[tid] = s[tid] - v;   // tid==NBKT: v=0 -> = E
}

// ---------------- pass B: scatter edges into coarse buckets (LDS cursors only) ----------------

__global__ __launch_bounds__(256) void k_scatterB(const int* __restrict__ ei,
                                                  const float* __restrict__ ew,
                                                  const int* __restrict__ mat,
                                                  const int* __restrict__ cbase,
                                                  int2* __restrict__ tmpA,
                                                  unsigned char* __restrict__ tmpD) {
    __shared__ int cur[NBKT];
    const int tid = threadIdx.x, blk = blockIdx.x;
    for (int i = tid; i < NBKT; i += 256)
        cur[i] = cbase[i] + mat[i * NBLKA + blk];
    __syncthreads();
    const int e0 = blk * EPB, e1 = e0 + EPB;
    for (int e = e0 + tid; e < e1; e += 256) {
        int r = ei[e];
        int c = ei[N_EDGES + e];
        int slot = atomicAdd(&cur[c >> 8], 1);
        tmpA[slot] = make_int2(r, __float_as_int(ew[e]));
        tmpD[slot] = (unsigned char)(c & 255);
    }
}

// ---------------- pass C: per-bucket fine count + scan + CSR emit + dinv ----------------
// csr.y gets ew * dinv[dst] (dst-side normalization fused here; src side in k_norm).

__global__ __launch_bounds__(256) void k_bucketC(const int* __restrict__ cbase,
                                                 const int2* __restrict__ tmpA,
                                                 const unsigned char* __restrict__ tmpD,
                                                 int2* __restrict__ csr,
                                                 int* __restrict__ cnt,
                                                 int* __restrict__ base,
                                                 float* __restrict__ dinv) {
    __shared__ int   c_cnt[256];
    __shared__ float c_deg[256];
    __shared__ int   c_scan[256];
    __shared__ int   c_cur[256];
    __shared__ float c_dnv[256];
    const int tid = threadIdx.x, b = blockIdx.x;
    const int s = cbase[b], e = cbase[b + 1];
    c_cnt[tid] = 0;
    c_deg[tid] = 0.f;
    __syncthreads();
    for (int j = s + tid; j < e; j += 256) {
        int d = tmpD[j];
        atomicAdd(&c_cnt[d], 1);
        atomicAdd(&c_deg[d], __int_as_float(tmpA[j].y));
    }
    __syncthreads();
    int v = c_cnt[tid];
    c_scan[tid] = v;
    __syncthreads();
    for (int off = 1; off < 256; off <<= 1) {
        int t = (tid >= off) ? c_scan[tid - off] : 0;
        __syncthreads();
        c_scan[tid] += t;
        __syncthreads();
    }
    int excl = c_scan[tid] - v;
    c_cur[tid] = excl;
    float dv = rsqrtf(1.0f + c_deg[tid]);        // self-loop weight 1
    c_dnv[tid] = dv;
    int node = b * 256 + tid;
    if (node < N_NODES) {
        cnt[node]  = v;
        base[node] = s + excl;
        dinv[node] = dv;
    }
    __syncthreads();
    for (int j = s + tid; j < e; j += 256) {
        int d = tmpD[j];
        int2 p = tmpA[j];
        int slot = atomicAdd(&c_cur[d], 1);
        csr[s + slot] = make_int2(p.x, __float_as_int(__int_as_float(p.y) * c_dnv[d]));
    }
}

// ---------------- norm pass: fold dinv[src] into csr weights (edge-parallel) ----------------

__global__ __launch_bounds__(256) void k_norm(int2* __restrict__ csr,
                                              const float* __restrict__ dinv) {
    int i = blockIdx.x * 256 + threadIdx.x;
    int2 p = csr[i];
    p.y = __float_as_int(__int_as_float(p.y) * dinv[p.x]);
    csr[i] = p;
}

// ---------------- layer 1 GEMM via MFMA: hpre(bf16) = x @ W1 ----------------

__global__ __launch_bounds__(256) void k_gemm1(const float* __restrict__ x,
                                               const float* __restrict__ W1,
                                               unsigned short* __restrict__ hpre) {
    __shared__ __align__(16) short Wt[64 * 512];   // 65536 B
    const int tid = threadIdx.x;

    {
        const int c  = tid & 63;
        const int kb = (tid >> 6) * 128;
        const int sw = (c & 7) << 3;
        for (int kk = 0; kk < 128; kk += 8) {
            short8 v;
#pragma unroll
            for (int j = 0; j < 8; j++)
                v[j] = (short)f2bf(W1[(size_t)(kb + kk + j) * D_HID + c]);
            *(short8*)&Wt[c * 512 + ((kb + kk) ^ sw)] = v;
        }
    }
    __syncthreads();

    const int widx = blockIdx.x * 4 + (tid >> 6);
    if (widx >= N_NODES / 16) return;
    const int lane = tid & 63;
    const int q  = lane >> 4;
    const int cn = lane & 15;
    const int r0 = widx * 16;
    const int sw = (cn & 7) << 3;

    floatx4 acc[4] = {{0,0,0,0},{0,0,0,0},{0,0,0,0},{0,0,0,0}};
    const float* xp = x + (size_t)(r0 + cn) * D_FEAT + q * 8;

#pragma unroll 4
    for (int k0 = 0; k0 < D_FEAT; k0 += 32) {
        float4 xa = *(const float4*)(xp + k0);
        float4 xb = *(const float4*)(xp + k0 + 4);
        short8 a = pack_bf16x8(xa, xb);
#pragma unroll
        for (int ct = 0; ct < 4; ct++) {
            short8 b = *(const short8*)&Wt[(ct * 16 + cn) * 512 + ((k0 + q * 8) ^ sw)];
            acc[ct] = __builtin_amdgcn_mfma_f32_16x16x32_bf16(a, b, acc[ct], 0, 0, 0);
        }
    }

#pragma unroll
    for (int ct = 0; ct < 4; ct++)
#pragma unroll
        for (int i = 0; i < 4; i++)
            hpre[(size_t)(r0 + q * 4 + i) * D_HID + ct * 16 + cn] = f2bf(acc[ct][i]);
}

// ---------------- layer 1 gather + fused layer-2 linear (relu(agg+b1) @ W2) ----------------
// One wave per node. 64 edges staged per coalesced int2 load; src/w broadcast via
// readlane -> SGPR; only per-edge VMEM is the 128B hpre row gather; 16 loads in flight.
// Out-of-range staged lanes get w=0 -> branchless full-width batches (no serial tail).

__global__ __launch_bounds__(256) void k_gather1(const int* __restrict__ base,
                                                 const int* __restrict__ cnt,
                                                 const int2* __restrict__ csr,
                                                 const unsigned short* __restrict__ hpre,
                                                 const float* __restrict__ dinv,
                                                 const float* __restrict__ b1,
                                                 const float* __restrict__ W2,
                                                 float* __restrict__ z) {
    __shared__ float hs[4][64];
    const int lane = threadIdx.x & 63;
    const int w = threadIdx.x >> 6;
    const int n = blockIdx.x * 4 + w;
    const int s = base[n], e = s + cnt[n];
    const float dn = dinv[n];

    float acc[16];
#pragma unroll
    for (int u = 0; u < 16; u++) acc[u] = 0.f;
    acc[0] = dn * dn * bf2f(hpre[(size_t)n * D_HID + lane]);   // self loop (norm = dn^2)

    for (int c = s; c < e; c += 64) {
        int idx = c + lane;
        int idxc = idx < e ? idx : (e - 1);
        int2 ed = csr[idxc];
        if (idx >= e) ed.y = 0;                 // zero weight for pad lanes
        int nc = e - c; if (nc > 64) nc = 64;
        for (int j = 0; j < nc; j += 16) {
#pragma unroll
            for (int u = 0; u < 16; u++) {
                int   src = __builtin_amdgcn_readlane(ed.x, j + u);
                float wj  = __uint_as_float((unsigned)__builtin_amdgcn_readlane(ed.y, j + u));
                const unsigned short* rp = hpre + ((size_t)src << 6);
                acc[u] = fmaf(wj, bf2f(rp[lane]), acc[u]);
            }
        }
    }

    float h = ((acc[0] + acc[1]) + (acc[2] + acc[3])) + ((acc[4] + acc[5]) + (acc[6] + acc[7]))
            + ((acc[8] + acc[9]) + (acc[10] + acc[11])) + ((acc[12] + acc[13]) + (acc[14] + acc[15]));
    h += b1[lane];
    h = h > 0.f ? h : 0.f;
    hs[w][lane] = h;                            // wave-private: no __syncthreads needed
    if (lane < N_CLS) {
        float a2 = 0.f;
#pragma unroll 8
        for (int k = 0; k < D_HID; k++)
            a2 += hs[w][k] * W2[k * N_CLS + lane];
        z[(size_t)n * ZSTR + lane] = a2;
    }
}

// ---------------- layer 2 gather + bias + log_softmax fused ----------------

__global__ __launch_bounds__(256) void k_gather2_lsm(const int* __restrict__ base,
                                                     const int* __restrict__ cnt,
                                                     const int2* __restrict__ csr,
                                                     const float* __restrict__ z,
                                                     const float* __restrict__ dinv,
                                                     const float* __restrict__ b2,
                                                     float* __restrict__ out) {
    const int lane = threadIdx.x & 63;
    const int n = blockIdx.x * 4 + (threadIdx.x >> 6);
    const bool act = lane < N_CLS;
    const int fl = act ? lane : (N_CLS - 1);    // clamped lane for safe loads
    const int s = base[n], e = s + cnt[n];
    const float dn = dinv[n];

    float acc[16];
#pragma unroll
    for (int u = 0; u < 16; u++) acc[u] = 0.f;
    acc[0] = dn * dn * z[(size_t)n * ZSTR + fl];

    for (int c = s; c < e; c += 64) {
        int idx = c + lane;
        int idxc = idx < e ? idx : (e - 1);
        int2 ed = csr[idxc];
        if (idx >= e) ed.y = 0;
        int nc = e - c; if (nc > 64) nc = 64;
        for (int j = 0; j < nc; j += 16) {
#pragma unroll
            for (int u = 0; u < 16; u++) {
                int   src = __builtin_amdgcn_readlane(ed.x, j + u);
                float wj  = __uint_as_float((unsigned)__builtin_amdgcn_readlane(ed.y, j + u));
                const float* rp = z + (size_t)src * ZSTR;
                acc[u] = fmaf(wj, rp[fl], acc[u]);
            }
        }
    }

    float logit = ((acc[0] + acc[1]) + (acc[2] + acc[3])) + ((acc[4] + acc[5]) + (acc[6] + acc[7]))
                + ((acc[8] + acc[9]) + (acc[10] + acc[11])) + ((acc[12] + acc[13]) + (acc[14] + acc[15]));
    logit += b2[fl];
    float m = act ? logit : -INFINITY;
    for (int off = 32; off; off >>= 1) m = fmaxf(m, __shfl_xor(m, off, 64));
    float ev = act ? expf(logit - m) : 0.f;
    float sum = ev;
    for (int off = 32; off; off >>= 1) sum += __shfl_xor(sum, off, 64);
    if (act) out[(size_t)n * N_CLS + lane] = logit - m - logf(sum);
}

// ---------------- launch ----------------

extern "C" void kernel_launch(void* const* d_in, const int* in_sizes, int n_in,
                              void* d_out, int out_size, void* d_ws, size_t ws_size,
                              hipStream_t stream) {
    const float* x  = (const float*)d_in[0];
    const int*   ei = (const int*)d_in[1];
    const float* ew = (const float*)d_in[2];
    const float* W1 = (const float*)d_in[3];
    const float* b1 = (const float*)d_in[4];
    const float* W2 = (const float*)d_in[5];
    const float* b2 = (const float*)d_in[6];
    float* out = (float*)d_out;

    // workspace layout (4B words):
    //   [0,      6.4M)   csr   int2[E]
    //   [6.4M,  12.8M)   tmpA  int2[E]  -- dead after C; hpre(bf16) at [6.4M, 9.6M)
    //   [9.6M,  14.4M)   z fp32[N][48] -- overlays tmpA tail / tmpD / mat / total / cbase (all dead)
    //   [12.8M, 13.6M)   tmpD  uchar[E] (dead before z written)
    //   [13.6M, ~13.7M)  mat/total/cbase (dead before z written)
    //   [14.4M, 14.7M)   cnt / base / dinv (live through gathers)
    int* ws = (int*)d_ws;
    int2*          csr  = (int2*)ws;
    int2*          tmpA = (int2*)(ws + 2 * (size_t)N_EDGES);
    unsigned char* tmpD = (unsigned char*)(ws + 4 * (size_t)N_EDGES);
    int*   mat   = ws + 4 * (size_t)N_EDGES + N_EDGES / 4;
    int*   total = mat + NBKT * NBLKA;
    int*   cbase = total + NBKT;
    unsigned short* hpre = (unsigned short*)tmpA;              // [6.4M, 9.6M)
    float* z = (float*)(ws + 2 * (size_t)N_EDGES + (size_t)N_NODES * D_HID / 2);  // word 9.6M
    int*   cnt  = ws + 2 * (size_t)N_EDGES + (size_t)N_NODES * D_HID / 2 + (size_t)N_NODES * ZSTR;
    int*   base = cnt + N_NODES;
    float* dinv = (float*)(base + N_NODES);

    k_histA   <<<NBLKA, 256, 0, stream>>>(ei, mat);
    k_scanRows<<<NBKT,  256, 0, stream>>>(mat, total);
    k_scanTot <<<1,     512, 0, stream>>>(total, cbase);
    k_scatterB<<<NBLKA, 256, 0, stream>>>(ei, ew, mat, cbase, tmpA, tmpD);
    k_bucketC <<<NBKT,  256, 0, stream>>>(cbase, tmpA, tmpD, csr, cnt, base, dinv);
    k_norm    <<<N_EDGES / 256, 256, 0, stream>>>(csr, dinv);
    k_gemm1   <<<(N_NODES / 16 + 3) / 4, 256, 0, stream>>>(x, W1, hpre);
    k_gather1 <<<N_NODES / 4, 256, 0, stream>>>(base, cnt, csr, hpre, dinv, b1, W2, z);
    k_gather2_lsm<<<N_NODES / 4, 256, 0, stream>>>(base, cnt, csr, z, dinv, b2, out);
}

// Round 7
// 706.533 us; speedup vs baseline: 1.1294x; 1.0290x over previous
//
#include <hip/hip_runtime.h>
#include <math.h>

#define N_NODES 100000
#define N_EDGES 3200000
#define D_FEAT  512
#define D_HID   64
#define N_CLS   40
#define ZSTR    64             /* padded z row stride (floats): 256B pow-2 rows */
#define NBKT    391            /* coarse buckets = ceil(N/256), bucket = dst >> 8 */
#define NBLKA   256            /* blocks in passes A/B */
#define EPB     (N_EDGES / NBLKA)   /* 12500 edges per block */

typedef __attribute__((ext_vector_type(8))) short short8;
typedef __attribute__((ext_vector_type(4))) float floatx4;

static __device__ __forceinline__ unsigned short f2bf(float f) {
    unsigned u = __float_as_uint(f);
    unsigned r = (u + 0x7FFFu + ((u >> 16) & 1u)) >> 16;   // RNE
    return (unsigned short)r;
}
static __device__ __forceinline__ float bf2f(unsigned short h) {
    return __uint_as_float(((unsigned)h) << 16);
}
static __device__ __forceinline__ short8 pack_bf16x8(float4 a, float4 b) {
    short8 r;
    r[0] = (short)f2bf(a.x); r[1] = (short)f2bf(a.y);
    r[2] = (short)f2bf(a.z); r[3] = (short)f2bf(a.w);
    r[4] = (short)f2bf(b.x); r[5] = (short)f2bf(b.y);
    r[6] = (short)f2bf(b.z); r[7] = (short)f2bf(b.w);
    return r;
}

// ---------------- pass A: per-block coarse histogram (no global atomics) ----------------

__global__ __launch_bounds__(256) void k_histA(const int* __restrict__ ei,
                                               int* __restrict__ mat) {
    __shared__ int hist[NBKT];
    const int tid = threadIdx.x, blk = blockIdx.x;
    for (int i = tid; i < NBKT; i += 256) hist[i] = 0;
    __syncthreads();
    const int e0 = blk * EPB, e1 = e0 + EPB;
    for (int e = e0 + tid; e < e1; e += 256)
        atomicAdd(&hist[ei[N_EDGES + e] >> 8], 1);
    __syncthreads();
    for (int i = tid; i < NBKT; i += 256) mat[i * NBLKA + blk] = hist[i];
}

// ---------------- S1: per-bucket exclusive scan across blocks + row totals ----------------

__global__ __launch_bounds__(256) void k_scanRows(int* __restrict__ mat,
                                                  int* __restrict__ total) {
    __shared__ int s[256];
    const int tid = threadIdx.x, bin = blockIdx.x;
    int v = mat[bin * NBLKA + tid];
    s[tid] = v;
    __syncthreads();
    for (int off = 1; off < 256; off <<= 1) {
        int t = (tid >= off) ? s[tid - off] : 0;
        __syncthreads();
        s[tid] += t;
        __syncthreads();
    }
    mat[bin * NBLKA + tid] = s[tid] - v;        // exclusive within bucket
    if (tid == 255) total[bin] = s[255];
}

// ---------------- S2: scan bucket totals -> coarse_base[NBKT+1] ----------------

__global__ __launch_bounds__(512) void k_scanTot(const int* __restrict__ total,
                                                 int* __restrict__ cbase) {
    __shared__ int s[512];
    const int tid = threadIdx.x;
    int v = (tid < NBKT) ? total[tid] : 0;
    s[tid] = v;
    __syncthreads();
    for (int off = 1; off < 512; off <<= 1) {
        int t = (tid >= off) ? s[tid - off] : 0;
        __syncthreads();
        s[tid] += t;
        __syncthreads();
    }
    if (tid <= NBKT) cbase[tid] = s[tid] - v;   // tid==NBKT: v=0 -> = E
}

// ---------------- pass B: scatter edges into coarse buckets (LDS cursors only) ----------------

__global__ __launch_bounds__(256) void k_scatterB(const int* __restrict__ ei,
                                                  const float* __restrict__ ew,
                                                  const int* __restrict__ mat,
                                                  const int* __restrict__ cbase,
                                                  int2* __restrict__ tmpA,
                                                  unsigned char* __restrict__ tmpD) {
    __shared__ int cur[NBKT];
    const int tid = threadIdx.x, blk = blockIdx.x;
    for (int i = tid; i < NBKT; i += 256)
        cur[i] = cbase[i] + mat[i * NBLKA + blk];
    __syncthreads();
    const int e0 = blk * EPB, e1 = e0 + EPB;
    for (int e = e0 + tid; e < e1; e += 256) {
        int r = ei[e];
        int c = ei[N_EDGES + e];
        int slot = atomicAdd(&cur[c >> 8], 1);
        tmpA[slot] = make_int2(r, __float_as_int(ew[e]));
        tmpD[slot] = (unsigned char)(c & 255);
    }
}

// ---------------- pass C: per-bucket fine count + scan + CSR emit + dinv ----------------
// csr.y gets ew * dinv[dst] (dst-side normalization fused here; src side in k_norm).

__global__ __launch_bounds__(256) void k_bucketC(const int* __restrict__ cbase,
                                                 const int2* __restrict__ tmpA,
                                                 const unsigned char* __restrict__ tmpD,
                                                 int2* __restrict__ csr,
                                                 int* __restrict__ cnt,
                                                 int* __restrict__ base,
                                                 float* __restrict__ dinv) {
    __shared__ int   c_cnt[256];
    __shared__ float c_deg[256];
    __shared__ int   c_scan[256];
    __shared__ int   c_cur[256];
    __shared__ float c_dnv[256];
    const int tid = threadIdx.x, b = blockIdx.x;
    const int s = cbase[b], e = cbase[b + 1];
    c_cnt[tid] = 0;
    c_deg[tid] = 0.f;
    __syncthreads();
    for (int j = s + tid; j < e; j += 256) {
        int d = tmpD[j];
        atomicAdd(&c_cnt[d], 1);
        atomicAdd(&c_deg[d], __int_as_float(tmpA[j].y));
    }
    __syncthreads();
    int v = c_cnt[tid];
    c_scan[tid] = v;
    __syncthreads();
    for (int off = 1; off < 256; off <<= 1) {
        int t = (tid >= off) ? c_scan[tid - off] : 0;
        __syncthreads();
        c_scan[tid] += t;
        __syncthreads();
    }
    int excl = c_scan[tid] - v;
    c_cur[tid] = excl;
    float dv = rsqrtf(1.0f + c_deg[tid]);        // self-loop weight 1
    c_dnv[tid] = dv;
    int node = b * 256 + tid;
    if (node < N_NODES) {
        cnt[node]  = v;
        base[node] = s + excl;
        dinv[node] = dv;
    }
    __syncthreads();
    for (int j = s + tid; j < e; j += 256) {
        int d = tmpD[j];
        int2 p = tmpA[j];
        int slot = atomicAdd(&c_cur[d], 1);
        csr[s + slot] = make_int2(p.x, __float_as_int(__int_as_float(p.y) * c_dnv[d]));
    }
}

// ---------------- norm pass: fold dinv[src] into csr weights (edge-parallel) ----------------

__global__ __launch_bounds__(256) void k_norm(int2* __restrict__ csr,
                                              const float* __restrict__ dinv) {
    int i = blockIdx.x * 256 + threadIdx.x;
    int2 p = csr[i];
    p.y = __float_as_int(__int_as_float(p.y) * dinv[p.x]);
    csr[i] = p;
}

// ---------------- layer 1 GEMM via MFMA: hpre(bf16) = x @ W1 ----------------

__global__ __launch_bounds__(256) void k_gemm1(const float* __restrict__ x,
                                               const float* __restrict__ W1,
                                               unsigned short* __restrict__ hpre) {
    __shared__ __align__(16) short Wt[64 * 512];   // 65536 B
    const int tid = threadIdx.x;

    {
        const int c  = tid & 63;
        const int kb = (tid >> 6) * 128;
        const int sw = (c & 7) << 3;
        for (int kk = 0; kk < 128; kk += 8) {
            short8 v;
#pragma unroll
            for (int j = 0; j < 8; j++)
                v[j] = (short)f2bf(W1[(size_t)(kb + kk + j) * D_HID + c]);
            *(short8*)&Wt[c * 512 + ((kb + kk) ^ sw)] = v;
        }
    }
    __syncthreads();

    const int widx = blockIdx.x * 4 + (tid >> 6);
    if (widx >= N_NODES / 16) return;
    const int lane = tid & 63;
    const int q  = lane >> 4;
    const int cn = lane & 15;
    const int r0 = widx * 16;
    const int sw = (cn & 7) << 3;

    floatx4 acc[4] = {{0,0,0,0},{0,0,0,0},{0,0,0,0},{0,0,0,0}};
    const float* xp = x + (size_t)(r0 + cn) * D_FEAT + q * 8;

#pragma unroll 4
    for (int k0 = 0; k0 < D_FEAT; k0 += 32) {
        float4 xa = *(const float4*)(xp + k0);
        float4 xb = *(const float4*)(xp + k0 + 4);
        short8 a = pack_bf16x8(xa, xb);
#pragma unroll
        for (int ct = 0; ct < 4; ct++) {
            short8 b = *(const short8*)&Wt[(ct * 16 + cn) * 512 + ((k0 + q * 8) ^ sw)];
            acc[ct] = __builtin_amdgcn_mfma_f32_16x16x32_bf16(a, b, acc[ct], 0, 0, 0);
        }
    }

#pragma unroll
    for (int ct = 0; ct < 4; ct++)
#pragma unroll
        for (int i = 0; i < 4; i++)
            hpre[(size_t)(r0 + q * 4 + i) * D_HID + ct * 16 + cn] = f2bf(acc[ct][i]);
}

// ---------------- layer 1 gather + fused layer-2 linear (relu(agg+b1) @ W2) ----------------
// One wave per node; 2 edges per wave-instruction: lanes 0-31 process edge 2p
// (dims 2q,2q+1 via one dword = 2 bf16), lanes 32-63 edge 2p+1. Edge (src,w)
// broadcast per half-wave via LDS stage. Self-loop init ONLY in vsel=0 half
// (the final shfl_xor(32) sums both halves — doubling was the round-6 bug).

__global__ __launch_bounds__(256) void k_gather1(const int* __restrict__ base,
                                                 const int* __restrict__ cnt,
                                                 const int2* __restrict__ csr,
                                                 const unsigned char* __restrict__ hpreB,
                                                 const float* __restrict__ dinv,
                                                 const float* __restrict__ b1,
                                                 const float* __restrict__ W2,
                                                 float* __restrict__ z) {
    __shared__ float hs[4][64];
    __shared__ int2  eds[4][64];
    const int lane = threadIdx.x & 63;
    const int w = threadIdx.x >> 6;
    const int n = blockIdx.x * 4 + w;
    const int s = base[n], e = s + cnt[n];
    const float dn = dinv[n];
    const int q = lane & 31;
    const int vsel = lane >> 5;
    const unsigned laneoff = (unsigned)q << 2;

    float accx[4] = {0.f, 0.f, 0.f, 0.f};
    float accy[4] = {0.f, 0.f, 0.f, 0.f};
    {
        unsigned pv = *(const unsigned*)(hpreB + (((unsigned)n) << 7) + laneoff);
        float dn2 = vsel ? 0.f : dn * dn;       // self-loop once (halves get summed)
        accx[0] = dn2 * __uint_as_float(pv << 16);
        accy[0] = dn2 * __uint_as_float(pv & 0xffff0000u);
    }

    for (int c = s; c < e; c += 64) {
        int idx = c + lane;
        int2 ed = csr[idx < e ? idx : (e - 1)];
        if (idx >= e) ed.y = 0;                 // zero weight for pad slots
        eds[w][lane] = ed;                      // wave-private stage (no barrier)
        int nc = e - c; if (nc > 64) nc = 64;
        for (int j = 0; j < nc; j += 16) {      // 8 edge-pairs per group
            int2 ep[8]; unsigned pv[8];
#pragma unroll
            for (int p = 0; p < 8; p++)
                ep[p] = eds[w][j + 2 * p + vsel];
#pragma unroll
            for (int p = 0; p < 8; p++)
                pv[p] = *(const unsigned*)(hpreB + (((unsigned)ep[p].x) << 7) + laneoff);
#pragma unroll
            for (int p = 0; p < 8; p++) {
                float wj = __int_as_float(ep[p].y);
                accx[p & 3] = fmaf(wj, __uint_as_float(pv[p] << 16), accx[p & 3]);
                accy[p & 3] = fmaf(wj, __uint_as_float(pv[p] & 0xffff0000u), accy[p & 3]);
            }
        }
    }

    float tx = (accx[0] + accx[1]) + (accx[2] + accx[3]);
    float ty = (accy[0] + accy[1]) + (accy[2] + accy[3]);
    tx += __shfl_xor(tx, 32, 64);
    ty += __shfl_xor(ty, 32, 64);
    if (lane < 32) {
        float h0 = tx + b1[2 * lane];
        float h1 = ty + b1[2 * lane + 1];
        hs[w][2 * lane]     = h0 > 0.f ? h0 : 0.f;
        hs[w][2 * lane + 1] = h1 > 0.f ? h1 : 0.f;
    }
    float a2 = 0.f;
    if (lane < N_CLS) {
#pragma unroll
        for (int k = 0; k < D_HID; k += 4) {
            float4 hv = *(const float4*)&hs[w][k];
            a2 += hv.x * W2[(k    ) * N_CLS + lane] + hv.y * W2[(k + 1) * N_CLS + lane]
                + hv.z * W2[(k + 2) * N_CLS + lane] + hv.w * W2[(k + 3) * N_CLS + lane];
        }
    }
    z[(size_t)n * ZSTR + lane] = (lane < N_CLS) ? a2 : 0.f;   // full 256B row, pad=0
}

// ---------------- layer 2 gather + bias + log_softmax fused (pair scheme, z f32) ----------------

__global__ __launch_bounds__(256) void k_gather2_lsm(const int* __restrict__ base,
                                                     const int* __restrict__ cnt,
                                                     const int2* __restrict__ csr,
                                                     const unsigned char* __restrict__ zB,
                                                     const float* __restrict__ dinv,
                                                     const float* __restrict__ b2,
                                                     float* __restrict__ out) {
    __shared__ int2 eds[4][64];
    const int lane = threadIdx.x & 63;
    const int w = threadIdx.x >> 6;
    const int n = blockIdx.x * 4 + w;
    const int s = base[n], e = s + cnt[n];
    const float dn = dinv[n];
    const int q = lane & 31;
    const int vsel = lane >> 5;
    const unsigned laneoff = (unsigned)q << 3;

    float accx[4] = {0.f, 0.f, 0.f, 0.f};
    float accy[4] = {0.f, 0.f, 0.f, 0.f};
    {
        float2 zv = *(const float2*)(zB + (((unsigned)n) << 8) + laneoff);
        float dn2 = vsel ? 0.f : dn * dn;       // self-loop once (halves get summed)
        accx[0] = dn2 * zv.x;
        accy[0] = dn2 * zv.y;
    }

    for (int c = s; c < e; c += 64) {
        int idx = c + lane;
        int2 ed = csr[idx < e ? idx : (e - 1)];
        if (idx >= e) ed.y = 0;
        eds[w][lane] = ed;
        int nc = e - c; if (nc > 64) nc = 64;
        for (int j = 0; j < nc; j += 16) {
            int2 ep[8]; float2 pv[8];
#pragma unroll
            for (int p = 0; p < 8; p++)
                ep[p] = eds[w][j + 2 * p + vsel];
#pragma unroll
            for (int p = 0; p < 8; p++)
                pv[p] = *(const float2*)(zB + (((unsigned)ep[p].x) << 8) + laneoff);
#pragma unroll
            for (int p = 0; p < 8; p++) {
                float wj = __int_as_float(ep[p].y);
                accx[p & 3] = fmaf(wj, pv[p].x, accx[p & 3]);
                accy[p & 3] = fmaf(wj, pv[p].y, accy[p & 3]);
            }
        }
    }

    float tx = (accx[0] + accx[1]) + (accx[2] + accx[3]);
    float ty = (accy[0] + accy[1]) + (accy[2] + accy[3]);
    tx += __shfl_xor(tx, 32, 64);
    ty += __shfl_xor(ty, 32, 64);

    const bool act2 = q < (N_CLS / 2);          // 20 pairs cover 40 classes
    float lg0 = 0.f, lg1 = 0.f;
    if (act2) {
        lg0 = tx + b2[2 * q];
        lg1 = ty + b2[2 * q + 1];
    }
    float m = act2 ? fmaxf(lg0, lg1) : -INFINITY;
    for (int off = 16; off; off >>= 1) m = fmaxf(m, __shfl_xor(m, off, 64));
    float ev = act2 ? (expf(lg0 - m) + expf(lg1 - m)) : 0.f;
    float sum = ev;
    for (int off = 16; off; off >>= 1) sum += __shfl_xor(sum, off, 64);
    float ls = logf(sum);
    if (lane < (N_CLS / 2)) {                   // low half writes pairs
        float2 o;
        o.x = lg0 - m - ls;
        o.y = lg1 - m - ls;
        *(float2*)(out + (size_t)n * N_CLS + 2 * lane) = o;
    }
}

// ---------------- launch ----------------

extern "C" void kernel_launch(void* const* d_in, const int* in_sizes, int n_in,
                              void* d_out, int out_size, void* d_ws, size_t ws_size,
                              hipStream_t stream) {
    const float* x  = (const float*)d_in[0];
    const int*   ei = (const int*)d_in[1];
    const float* ew = (const float*)d_in[2];
    const float* W1 = (const float*)d_in[3];
    const float* b1 = (const float*)d_in[4];
    const float* W2 = (const float*)d_in[5];
    const float* b2 = (const float*)d_in[6];
    float* out = (float*)d_out;

    // workspace layout (4B words):
    //   [0,      6.4M)   csr   int2[E]
    //   [6.4M,  12.8M)   tmpA  int2[E]  -- dead after C; hpre(bf16) at [6.4M, 9.6M)
    //   [9.6M,  16.0M)   z fp32[N][64] -- overlays tmpA tail/tmpD/mat/total/cbase (all dead pre-gather1)
    //   [12.8M, 13.6M)   tmpD  uchar[E] (dead before z written)
    //   [13.6M, ~13.71M) mat/total/cbase (dead before z written)
    //   [16.0M, 16.3M)   cnt / base / dinv (live through gathers)
    int* ws = (int*)d_ws;
    int2*          csr  = (int2*)ws;
    int2*          tmpA = (int2*)(ws + 2 * (size_t)N_EDGES);
    unsigned char* tmpD = (unsigned char*)(ws + 4 * (size_t)N_EDGES);
    int*   mat   = ws + 4 * (size_t)N_EDGES + N_EDGES / 4;
    int*   total = mat + NBKT * NBLKA;
    int*   cbase = total + NBKT;
    unsigned short* hpre = (unsigned short*)tmpA;              // [6.4M, 9.6M)
    float* z = (float*)(ws + 2 * (size_t)N_EDGES + (size_t)N_NODES * D_HID / 2);  // word 9.6M
    int*   cnt  = ws + 2 * (size_t)N_EDGES + (size_t)N_NODES * D_HID / 2 + (size_t)N_NODES * ZSTR;
    int*   base = cnt + N_NODES;
    float* dinv = (float*)(base + N_NODES);

    k_histA   <<<NBLKA, 256, 0, stream>>>(ei, mat);
    k_scanRows<<<NBKT,  256, 0, stream>>>(mat, total);
    k_scanTot <<<1,     512, 0, stream>>>(total, cbase);
    k_scatterB<<<NBLKA, 256, 0, stream>>>(ei, ew, mat, cbase, tmpA, tmpD);
    k_bucketC <<<NBKT,  256, 0, stream>>>(cbase, tmpA, tmpD, csr, cnt, base, dinv);
    k_norm    <<<N_EDGES / 256, 256, 0, stream>>>(csr, dinv);
    k_gemm1   <<<(N_NODES / 16 + 3) / 4, 256, 0, stream>>>(x, W1, hpre);
    k_gather1 <<<N_NODES / 4, 256, 0, stream>>>(base, cnt, csr,
                                                (const unsigned char*)hpre, dinv, b1, W2, z);
    k_gather2_lsm<<<N_NODES / 4, 256, 0, stream>>>(base, cnt, csr,
                                                   (const unsigned char*)z, dinv, b2, out);
}

// Round 8
// 655.694 us; speedup vs baseline: 1.2170x; 1.0775x over previous
//
#include <hip/hip_runtime.h>
#include <math.h>

#define N_NODES 100000
#define N_EDGES 3200000
#define D_FEAT  512
#define D_HID   64
#define N_CLS   40
#define NBKT    391            /* coarse buckets = ceil(N/256), bucket = dst >> 8 */
#define NBLKA   256            /* blocks in passes A/B */
#define EPB     (N_EDGES / NBLKA)   /* 12500 edges per block */

typedef __attribute__((ext_vector_type(8))) short short8;
typedef __attribute__((ext_vector_type(4))) float floatx4;

static __device__ __forceinline__ unsigned short f2bf(float f) {
    unsigned u = __float_as_uint(f);
    unsigned r = (u + 0x7FFFu + ((u >> 16) & 1u)) >> 16;   // RNE
    return (unsigned short)r;
}
static __device__ __forceinline__ float bf2f(unsigned short h) {
    return __uint_as_float(((unsigned)h) << 16);
}
static __device__ __forceinline__ short8 pack_bf16x8(float4 a, float4 b) {
    short8 r;
    r[0] = (short)f2bf(a.x); r[1] = (short)f2bf(a.y);
    r[2] = (short)f2bf(a.z); r[3] = (short)f2bf(a.w);
    r[4] = (short)f2bf(b.x); r[5] = (short)f2bf(b.y);
    r[6] = (short)f2bf(b.z); r[7] = (short)f2bf(b.w);
    return r;
}

// ---------------- pass A: per-block coarse histogram (no global atomics) ----------------

__global__ __launch_bounds__(256) void k_histA(const int* __restrict__ ei,
                                               int* __restrict__ mat) {
    __shared__ int hist[NBKT];
    const int tid = threadIdx.x, blk = blockIdx.x;
    for (int i = tid; i < NBKT; i += 256) hist[i] = 0;
    __syncthreads();
    const int e0 = blk * EPB, e1 = e0 + EPB;
    for (int e = e0 + tid; e < e1; e += 256)
        atomicAdd(&hist[ei[N_EDGES + e] >> 8], 1);
    __syncthreads();
    for (int i = tid; i < NBKT; i += 256) mat[i * NBLKA + blk] = hist[i];
}

// ---------------- S1: per-bucket exclusive scan across blocks + row totals ----------------

__global__ __launch_bounds__(256) void k_scanRows(int* __restrict__ mat,
                                                  int* __restrict__ total) {
    __shared__ int s[256];
    const int tid = threadIdx.x, bin = blockIdx.x;
    int v = mat[bin * NBLKA + tid];
    s[tid] = v;
    __syncthreads();
    for (int off = 1; off < 256; off <<= 1) {
        int t = (tid >= off) ? s[tid - off] : 0;
        __syncthreads();
        s[tid] += t;
        __syncthreads();
    }
    mat[bin * NBLKA + tid] = s[tid] - v;        // exclusive within bucket
    if (tid == 255) total[bin] = s[255];
}

// ---------------- S2: scan bucket totals -> coarse_base[NBKT+1] ----------------

__global__ __launch_bounds__(512) void k_scanTot(const int* __restrict__ total,
                                                 int* __restrict__ cbase) {
    __shared__ int s[512];
    const int tid = threadIdx.x;
    int v = (tid < NBKT) ? total[tid] : 0;
    s[tid] = v;
    __syncthreads();
    for (int off = 1; off < 512; off <<= 1) {
        int t = (tid >= off) ? s[tid - off] : 0;
        __syncthreads();
        s[tid] += t;
        __syncthreads();
    }
    if (tid <= NBKT) cbase[tid] = s[tid] - v;   // tid==NBKT: v=0 -> = E
}

// ---------------- pass B: scatter edges into coarse buckets (LDS cursors only) ----------------

__global__ __launch_bounds__(256) void k_scatterB(const int* __restrict__ ei,
                                                  const float* __restrict__ ew,
                                                  const int* __restrict__ mat,
                                                  const int* __restrict__ cbase,
                                                  int2* __restrict__ tmpA,
                                                  unsigned char* __restrict__ tmpD) {
    __shared__ int cur[NBKT];
    const int tid = threadIdx.x, blk = blockIdx.x;
    for (int i = tid; i < NBKT; i += 256)
        cur[i] = cbase[i] + mat[i * NBLKA + blk];
    __syncthreads();
    const int e0 = blk * EPB, e1 = e0 + EPB;
    for (int e = e0 + tid; e < e1; e += 256) {
        int r = ei[e];
        int c = ei[N_EDGES + e];
        int slot = atomicAdd(&cur[c >> 8], 1);
        tmpA[slot] = make_int2(r, __float_as_int(ew[e]));
        tmpD[slot] = (unsigned char)(c & 255);
    }
}

// ---------------- pass C: per-bucket fine count + scan + CSR emit + dinv ----------------
// csr.y gets ew * dinv[dst] (dst-side normalization fused here; src side in k_norm).

__global__ __launch_bounds__(256) void k_bucketC(const int* __restrict__ cbase,
                                                 const int2* __restrict__ tmpA,
                                                 const unsigned char* __restrict__ tmpD,
                                                 int2* __restrict__ csr,
                                                 int* __restrict__ cnt,
                                                 int* __restrict__ base,
                                                 float* __restrict__ dinv) {
    __shared__ int   c_cnt[256];
    __shared__ float c_deg[256];
    __shared__ int   c_scan[256];
    __shared__ int   c_cur[256];
    __shared__ float c_dnv[256];
    const int tid = threadIdx.x, b = blockIdx.x;
    const int s = cbase[b], e = cbase[b + 1];
    c_cnt[tid] = 0;
    c_deg[tid] = 0.f;
    __syncthreads();
    for (int j = s + tid; j < e; j += 256) {
        int d = tmpD[j];
        atomicAdd(&c_cnt[d], 1);
        atomicAdd(&c_deg[d], __int_as_float(tmpA[j].y));
    }
    __syncthreads();
    int v = c_cnt[tid];
    c_scan[tid] = v;
    __syncthreads();
    for (int off = 1; off < 256; off <<= 1) {
        int t = (tid >= off) ? c_scan[tid - off] : 0;
        __syncthreads();
        c_scan[tid] += t;
        __syncthreads();
    }
    int excl = c_scan[tid] - v;
    c_cur[tid] = excl;
    float dv = rsqrtf(1.0f + c_deg[tid]);        // self-loop weight 1
    c_dnv[tid] = dv;
    int node = b * 256 + tid;
    if (node < N_NODES) {
        cnt[node]  = v;
        base[node] = s + excl;
        dinv[node] = dv;
    }
    __syncthreads();
    for (int j = s + tid; j < e; j += 256) {
        int d = tmpD[j];
        int2 p = tmpA[j];
        int slot = atomicAdd(&c_cur[d], 1);
        csr[s + slot] = make_int2(p.x, __float_as_int(__int_as_float(p.y) * c_dnv[d]));
    }
}

// ---------------- norm pass: fold dinv[src] into csr weights (edge-parallel) ----------------

__global__ __launch_bounds__(256) void k_norm(int2* __restrict__ csr,
                                              const float* __restrict__ dinv) {
    int i = blockIdx.x * 256 + threadIdx.x;
    int2 p = csr[i];
    p.y = __float_as_int(__int_as_float(p.y) * dinv[p.x]);
    csr[i] = p;
}

// ---------------- layer 1 GEMM via MFMA: hpre(bf16) = x @ W1 ----------------

__global__ __launch_bounds__(256) void k_gemm1(const float* __restrict__ x,
                                               const float* __restrict__ W1,
                                               unsigned short* __restrict__ hpre) {
    __shared__ __align__(16) short Wt[64 * 512];   // 65536 B
    const int tid = threadIdx.x;

    {
        const int c  = tid & 63;
        const int kb = (tid >> 6) * 128;
        const int sw = (c & 7) << 3;
        for (int kk = 0; kk < 128; kk += 8) {
            short8 v;
#pragma unroll
            for (int j = 0; j < 8; j++)
                v[j] = (short)f2bf(W1[(size_t)(kb + kk + j) * D_HID + c]);
            *(short8*)&Wt[c * 512 + ((kb + kk) ^ sw)] = v;
        }
    }
    __syncthreads();

    const int widx = blockIdx.x * 4 + (tid >> 6);
    if (widx >= N_NODES / 16) return;
    const int lane = tid & 63;
    const int q  = lane >> 4;
    const int cn = lane & 15;
    const int r0 = widx * 16;
    const int sw = (cn & 7) << 3;

    floatx4 acc[4] = {{0,0,0,0},{0,0,0,0},{0,0,0,0},{0,0,0,0}};
    const float* xp = x + (size_t)(r0 + cn) * D_FEAT + q * 8;

#pragma unroll 4
    for (int k0 = 0; k0 < D_FEAT; k0 += 32) {
        float4 xa = *(const float4*)(xp + k0);
        float4 xb = *(const float4*)(xp + k0 + 4);
        short8 a = pack_bf16x8(xa, xb);
#pragma unroll
        for (int ct = 0; ct < 4; ct++) {
            short8 b = *(const short8*)&Wt[(ct * 16 + cn) * 512 + ((k0 + q * 8) ^ sw)];
            acc[ct] = __builtin_amdgcn_mfma_f32_16x16x32_bf16(a, b, acc[ct], 0, 0, 0);
        }
    }

#pragma unroll
    for (int ct = 0; ct < 4; ct++)
#pragma unroll
        for (int i = 0; i < 4; i++)
            hpre[(size_t)(r0 + q * 4 + i) * D_HID + ct * 16 + cn] = f2bf(acc[ct][i]);
}

// ---------------- layer 1 gather + fused layer-2 linear (relu(agg+b1) @ W2) ----------------
// One wave per node; 2 edges per wave-instruction: lanes 0-31 process edge 2p
// (dims 2q,2q+1 via one dword = 2 bf16), lanes 32-63 edge 2p+1. Edge (src,w)
// broadcast per half-wave via LDS stage. Self-loop init ONLY in vsel=0 half.
// Output z stored as bf16 rows of 64 (128B) to halve gather2's L2-miss traffic.

__global__ __launch_bounds__(256) void k_gather1(const int* __restrict__ base,
                                                 const int* __restrict__ cnt,
                                                 const int2* __restrict__ csr,
                                                 const unsigned char* __restrict__ hpreB,
                                                 const float* __restrict__ dinv,
                                                 const float* __restrict__ b1,
                                                 const float* __restrict__ W2,
                                                 unsigned short* __restrict__ z16) {
    __shared__ float hs[4][64];
    __shared__ int2  eds[4][64];
    const int lane = threadIdx.x & 63;
    const int w = threadIdx.x >> 6;
    const int n = blockIdx.x * 4 + w;
    const int s = base[n], e = s + cnt[n];
    const float dn = dinv[n];
    const int q = lane & 31;
    const int vsel = lane >> 5;
    const unsigned laneoff = (unsigned)q << 2;

    float accx[4] = {0.f, 0.f, 0.f, 0.f};
    float accy[4] = {0.f, 0.f, 0.f, 0.f};
    {
        unsigned pv = *(const unsigned*)(hpreB + (((unsigned)n) << 7) + laneoff);
        float dn2 = vsel ? 0.f : dn * dn;       // self-loop once (halves get summed)
        accx[0] = dn2 * __uint_as_float(pv << 16);
        accy[0] = dn2 * __uint_as_float(pv & 0xffff0000u);
    }

    for (int c = s; c < e; c += 64) {
        int idx = c + lane;
        int2 ed = csr[idx < e ? idx : (e - 1)];
        if (idx >= e) ed.y = 0;                 // zero weight for pad slots
        eds[w][lane] = ed;                      // wave-private stage (no barrier)
        int nc = e - c; if (nc > 64) nc = 64;
        for (int j = 0; j < nc; j += 16) {      // 8 edge-pairs per group
            int2 ep[8]; unsigned pv[8];
#pragma unroll
            for (int p = 0; p < 8; p++)
                ep[p] = eds[w][j + 2 * p + vsel];
#pragma unroll
            for (int p = 0; p < 8; p++)
                pv[p] = *(const unsigned*)(hpreB + (((unsigned)ep[p].x) << 7) + laneoff);
#pragma unroll
            for (int p = 0; p < 8; p++) {
                float wj = __int_as_float(ep[p].y);
                accx[p & 3] = fmaf(wj, __uint_as_float(pv[p] << 16), accx[p & 3]);
                accy[p & 3] = fmaf(wj, __uint_as_float(pv[p] & 0xffff0000u), accy[p & 3]);
            }
        }
    }

    float tx = (accx[0] + accx[1]) + (accx[2] + accx[3]);
    float ty = (accy[0] + accy[1]) + (accy[2] + accy[3]);
    tx += __shfl_xor(tx, 32, 64);
    ty += __shfl_xor(ty, 32, 64);
    if (lane < 32) {
        float h0 = tx + b1[2 * lane];
        float h1 = ty + b1[2 * lane + 1];
        hs[w][2 * lane]     = h0 > 0.f ? h0 : 0.f;
        hs[w][2 * lane + 1] = h1 > 0.f ? h1 : 0.f;
    }
    float a2 = 0.f;
    if (lane < N_CLS) {
#pragma unroll
        for (int k = 0; k < D_HID; k += 4) {
            float4 hv = *(const float4*)&hs[w][k];
            a2 += hv.x * W2[(k    ) * N_CLS + lane] + hv.y * W2[(k + 1) * N_CLS + lane]
                + hv.z * W2[(k + 2) * N_CLS + lane] + hv.w * W2[(k + 3) * N_CLS + lane];
        }
    }
    // full 128B bf16 row, pad dims 40..63 = 0 (re-written every launch: no
    // dependence on workspace poisoning state)
    z16[(size_t)n * D_HID + lane] = (lane < N_CLS) ? f2bf(a2) : 0;
}

// ---------------- layer 2 gather + bias + log_softmax fused (pair scheme, z bf16) ----------------

__global__ __launch_bounds__(256) void k_gather2_lsm(const int* __restrict__ base,
                                                     const int* __restrict__ cnt,
                                                     const int2* __restrict__ csr,
                                                     const unsigned char* __restrict__ zB,
                                                     const float* __restrict__ dinv,
                                                     const float* __restrict__ b2,
                                                     float* __restrict__ out) {
    __shared__ int2 eds[4][64];
    const int lane = threadIdx.x & 63;
    const int w = threadIdx.x >> 6;
    const int n = blockIdx.x * 4 + w;
    const int s = base[n], e = s + cnt[n];
    const float dn = dinv[n];
    const int q = lane & 31;
    const int vsel = lane >> 5;
    const unsigned laneoff = (unsigned)q << 2;

    float accx[4] = {0.f, 0.f, 0.f, 0.f};
    float accy[4] = {0.f, 0.f, 0.f, 0.f};
    {
        unsigned pv = *(const unsigned*)(zB + (((unsigned)n) << 7) + laneoff);
        float dn2 = vsel ? 0.f : dn * dn;       // self-loop once (halves get summed)
        accx[0] = dn2 * __uint_as_float(pv << 16);
        accy[0] = dn2 * __uint_as_float(pv & 0xffff0000u);
    }

    for (int c = s; c < e; c += 64) {
        int idx = c + lane;
        int2 ed = csr[idx < e ? idx : (e - 1)];
        if (idx >= e) ed.y = 0;
        eds[w][lane] = ed;
        int nc = e - c; if (nc > 64) nc = 64;
        for (int j = 0; j < nc; j += 16) {
            int2 ep[8]; unsigned pv[8];
#pragma unroll
            for (int p = 0; p < 8; p++)
                ep[p] = eds[w][j + 2 * p + vsel];
#pragma unroll
            for (int p = 0; p < 8; p++)
                pv[p] = *(const unsigned*)(zB + (((unsigned)ep[p].x) << 7) + laneoff);
#pragma unroll
            for (int p = 0; p < 8; p++) {
                float wj = __int_as_float(ep[p].y);
                accx[p & 3] = fmaf(wj, __uint_as_float(pv[p] << 16), accx[p & 3]);
                accy[p & 3] = fmaf(wj, __uint_as_float(pv[p] & 0xffff0000u), accy[p & 3]);
            }
        }
    }

    float tx = (accx[0] + accx[1]) + (accx[2] + accx[3]);
    float ty = (accy[0] + accy[1]) + (accy[2] + accy[3]);
    tx += __shfl_xor(tx, 32, 64);
    ty += __shfl_xor(ty, 32, 64);

    const bool act2 = q < (N_CLS / 2);          // 20 pairs cover 40 classes
    float lg0 = 0.f, lg1 = 0.f;
    if (act2) {
        lg0 = tx + b2[2 * q];
        lg1 = ty + b2[2 * q + 1];
    }
    float m = act2 ? fmaxf(lg0, lg1) : -INFINITY;
    for (int off = 16; off; off >>= 1) m = fmaxf(m, __shfl_xor(m, off, 64));
    float ev = act2 ? (expf(lg0 - m) + expf(lg1 - m)) : 0.f;
    float sum = ev;
    for (int off = 16; off; off >>= 1) sum += __shfl_xor(sum, off, 64);
    float ls = logf(sum);
    if (lane < (N_CLS / 2)) {                   // low half writes pairs
        float2 o;
        o.x = lg0 - m - ls;
        o.y = lg1 - m - ls;
        *(float2*)(out + (size_t)n * N_CLS + 2 * lane) = o;
    }
}

// ---------------- launch ----------------

extern "C" void kernel_launch(void* const* d_in, const int* in_sizes, int n_in,
                              void* d_out, int out_size, void* d_ws, size_t ws_size,
                              hipStream_t stream) {
    const float* x  = (const float*)d_in[0];
    const int*   ei = (const int*)d_in[1];
    const float* ew = (const float*)d_in[2];
    const float* W1 = (const float*)d_in[3];
    const float* b1 = (const float*)d_in[4];
    const float* W2 = (const float*)d_in[5];
    const float* b2 = (const float*)d_in[6];
    float* out = (float*)d_out;

    // workspace layout (4B words):
    //   [0,      6.4M)   csr   int2[E]
    //   [6.4M,  12.8M)   tmpA  int2[E]  -- dead after C; hpre(bf16) [6.4M, 9.6M),
    //                                      z16(bf16)  [9.6M, 12.8M)
    //   [12.8M, 13.6M)   tmpD  uchar[E]
    //   [13.6M, ~13.71M) mat/total/cbase
    //   [16.0M, 16.3M)   cnt / base / dinv (live through gathers)
    int* ws = (int*)d_ws;
    int2*          csr  = (int2*)ws;
    int2*          tmpA = (int2*)(ws + 2 * (size_t)N_EDGES);
    unsigned char* tmpD = (unsigned char*)(ws + 4 * (size_t)N_EDGES);
    int*   mat   = ws + 4 * (size_t)N_EDGES + N_EDGES / 4;
    int*   total = mat + NBKT * NBLKA;
    int*   cbase = total + NBKT;
    unsigned short* hpre = (unsigned short*)tmpA;              // [6.4M, 9.6M)
    unsigned short* z16  = hpre + (size_t)N_NODES * D_HID;     // [9.6M, 12.8M)
    int*   cnt  = ws + 16000000;
    int*   base = cnt + N_NODES;
    float* dinv = (float*)(base + N_NODES);

    k_histA   <<<NBLKA, 256, 0, stream>>>(ei, mat);
    k_scanRows<<<NBKT,  256, 0, stream>>>(mat, total);
    k_scanTot <<<1,     512, 0, stream>>>(total, cbase);
    k_scatterB<<<NBLKA, 256, 0, stream>>>(ei, ew, mat, cbase, tmpA, tmpD);
    k_bucketC <<<NBKT,  256, 0, stream>>>(cbase, tmpA, tmpD, csr, cnt, base, dinv);
    k_norm    <<<N_EDGES / 256, 256, 0, stream>>>(csr, dinv);
    k_gemm1   <<<(N_NODES / 16 + 3) / 4, 256, 0, stream>>>(x, W1, hpre);
    k_gather1 <<<N_NODES / 4, 256, 0, stream>>>(base, cnt, csr,
                                                (const unsigned char*)hpre, dinv, b1, W2, z16);
    k_gather2_lsm<<<N_NODES / 4, 256, 0, stream>>>(base, cnt, csr,
                                                   (const unsigned char*)z16, dinv, b2, out);
}